// Round 2
// baseline (402.223 us; speedup 1.0000x reference)
//
#include <hip/hip_runtime.h>
#include <hip/hip_bf16.h>
#include <cstdint>

typedef __attribute__((ext_vector_type(8))) short bf16x8;
typedef __attribute__((ext_vector_type(4))) float f32x4;

#define MFMA16(a, b, c) __builtin_amdgcn_mfma_f32_16x16x32_bf16(a, b, c, 0, 0, 0)

static __device__ __forceinline__ ushort f2b(float f) {
  union { float f; uint32_t u; } v; v.f = f;
  uint32_t u = v.u;
  uint32_t r = (u + 0x7FFFu + ((u >> 16) & 1u)) >> 16;
  return (ushort)r;
}

// ---------- fp32 -> bf16 convert (n4 = n/4 float4 chunks) ----------
__global__ void cvt_f32_bf16(const float* __restrict__ in, ushort* __restrict__ out, int n4) {
  int i = blockIdx.x * blockDim.x + threadIdx.x;
  if (i >= n4) return;
  const float4 v = ((const float4*)in)[i];
  ushort4 o;
  o.x = f2b(v.x); o.y = f2b(v.y); o.z = f2b(v.z); o.w = f2b(v.w);
  ((ushort4*)out)[i] = o;
}

// ---------- GEMM: C[m][n] = sum_k A[m][k] * W[n][k] + bias[n] ----------
// EPI=0: scatter q,k -> [B*H][T][64] bf16; v -> V^T [B*H][64][T] bf16
// EPI=1: fp32 out [M][N]
template<int EPI>
__global__ __launch_bounds__(256) void gemm_bt(
    const ushort* __restrict__ A,    // [M][K] bf16
    const ushort* __restrict__ W,    // [N][K] bf16
    const float* __restrict__ bias,  // [N]
    int M, int N, int K,
    ushort* __restrict__ q_ws, ushort* __restrict__ k_ws, ushort* __restrict__ v_ws,
    float* __restrict__ out) {
  __shared__ ushort As[128][72];  // pad: 144B row stride -> 2-way bank alias (free)
  __shared__ ushort Bs[128][72];
  const int tid = threadIdx.x;
  const int m0 = blockIdx.y * 128, n0 = blockIdx.x * 128;
  const int lane = tid & 63, w = tid >> 6;
  const int lr = lane & 15, lg = lane >> 4;
  const int wm = (w >> 1) * 64, wn = (w & 1) * 64;
  f32x4 acc[4][4] = {};

  for (int k0 = 0; k0 < K; k0 += 64) {
    __syncthreads();
#pragma unroll
    for (int it = 0; it < 4; ++it) {
      int chunk = tid + it * 256;      // 0..1023
      int r = chunk >> 3;              // 0..127
      int c = (chunk & 7) * 8;         // 0..56
      *(uint4*)&As[r][c] = *(const uint4*)&A[(size_t)(m0 + r) * K + k0 + c];
      *(uint4*)&Bs[r][c] = *(const uint4*)&W[(size_t)(n0 + r) * K + k0 + c];
    }
    __syncthreads();
#pragma unroll
    for (int kk = 0; kk < 2; ++kk) {
      bf16x8 a[4], b[4];
#pragma unroll
      for (int mi = 0; mi < 4; ++mi)
        a[mi] = *(const bf16x8*)&As[wm + mi * 16 + lr][kk * 32 + lg * 8];
#pragma unroll
      for (int ni = 0; ni < 4; ++ni)
        b[ni] = *(const bf16x8*)&Bs[wn + ni * 16 + lr][kk * 32 + lg * 8];
#pragma unroll
      for (int mi = 0; mi < 4; ++mi)
#pragma unroll
        for (int ni = 0; ni < 4; ++ni)
          acc[mi][ni] = MFMA16(a[mi], b[ni], acc[mi][ni]);
    }
  }

#pragma unroll
  for (int mi = 0; mi < 4; ++mi) {
#pragma unroll
    for (int ni = 0; ni < 4; ++ni) {
      const int rowb = m0 + wm + mi * 16 + lg * 4;  // C/D: row=(lane>>4)*4+reg, col=lane&15
      const int col = n0 + wn + ni * 16 + lr;
      float v[4];
#pragma unroll
      for (int i = 0; i < 4; ++i) v[i] = acc[mi][ni][i] + bias[col];
      if (EPI == 0) {
        const int sel = col >> 10;        // uniform per block (n0 multiple of 128)
        const int rem = col & 1023;
        const int h = rem >> 6, d = rem & 63;
        const int bb = rowb >> 11, t0 = rowb & 2047;
        if (sel == 2) {
          // V^T: [bh][d][t] — 4 regs are t-contiguous -> packed 8B store
          ushort4 st;
          st.x = f2b(v[0]); st.y = f2b(v[1]); st.z = f2b(v[2]); st.w = f2b(v[3]);
          *(ushort4*)&v_ws[((size_t)(bb * 16 + h) * 64 + d) * 2048 + t0] = st;
        } else {
          ushort* dst = (sel == 0) ? q_ws : k_ws;
#pragma unroll
          for (int i = 0; i < 4; ++i)
            dst[((size_t)(bb * 16 + h) * 2048 + t0 + i) * 64 + d] = f2b(v[i]);
        }
      } else {
#pragma unroll
        for (int i = 0; i < 4; ++i)
          out[(size_t)(rowb + i) * N + col] = v[i];
      }
    }
  }
}

// ---------- causal flash attention v2: 1 wave = 32 q rows, KVBLK=64 ----------
// 4 independent waves per block (per-wave LDS region, no barriers)
__global__ __launch_bounds__(256) void attn_v2(
    const ushort* __restrict__ Q, const ushort* __restrict__ K,
    const ushort* __restrict__ VT, ushort* __restrict__ O /* [B][T][C] bf16 */) {
  const int qblk = blockIdx.x >> 6;  // 0..15  (qblk-major: same-bh blocks share an XCD)
  const int bh = blockIdx.x & 63;
  const int tid = threadIdx.x;
  const int w = tid >> 6;
  const int lane = tid & 63;
  const int lr = lane & 15, lg = lane >> 4;
  const int q0w = qblk * 128 + w * 32;
  const int b = bh >> 4, h = bh & 15;
  const size_t base = (size_t)bh * 2048 * 64;
  const ushort* Qb = Q + base;
  const ushort* Kb = K + base;
  const ushort* VTb = VT + base;  // [64][2048]

  __shared__ ushort Plds[4][16][72];  // per-wave region, padded (2-way alias only)

  bf16x8 aq[2][2];
#pragma unroll
  for (int m = 0; m < 2; ++m)
#pragma unroll
    for (int kk = 0; kk < 2; ++kk)
      aq[m][kk] = *(const bf16x8*)&Qb[(size_t)(q0w + m * 16 + lr) * 64 + kk * 32 + lg * 8];

  f32x4 o[2][4] = {};
  float mi[2][4], li[2][4];
#pragma unroll
  for (int m = 0; m < 2; ++m)
#pragma unroll
    for (int i = 0; i < 4; ++i) { mi[m][i] = -INFINITY; li[m][i] = 0.f; }

  const int kend_tile = (q0w + 31) >> 6;
  for (int kt = 0; kt <= kend_tile; ++kt) {
    const int k0 = kt << 6;
#pragma unroll
    for (int m = 0; m < 2; ++m) {
      const int qm = q0w + m * 16;
      // ---- QK^T: S[16 rows][64 cols] ----
      f32x4 s[4];
#pragma unroll
      for (int h2 = 0; h2 < 4; ++h2) {
        const ushort* kp = &Kb[(size_t)(k0 + h2 * 16 + lr) * 64 + lg * 8];
        bf16x8 bk0 = *(const bf16x8*)kp;
        bf16x8 bk1 = *(const bf16x8*)(kp + 32);
        f32x4 t = {};
        t = MFMA16(aq[m][0], bk0, t);
        t = MFMA16(aq[m][1], bk1, t);
        s[h2] = t;
      }
      // ---- online softmax ----
      const bool domask = (k0 + 63 > qm);
      f32x4 p[4];
#pragma unroll
      for (int i = 0; i < 4; ++i) {
        const int row = qm + lg * 4 + i;
        if (domask) {
#pragma unroll
          for (int h2 = 0; h2 < 4; ++h2) {
            const int col = k0 + h2 * 16 + lr;
            s[h2][i] = (col <= row) ? s[h2][i] * 0.125f : -1e30f;
          }
        } else {
#pragma unroll
          for (int h2 = 0; h2 < 4; ++h2) s[h2][i] *= 0.125f;
        }
        float mx = fmaxf(fmaxf(s[0][i], s[1][i]), fmaxf(s[2][i], s[3][i]));
        mx = fmaxf(mx, __shfl_xor(mx, 1));
        mx = fmaxf(mx, __shfl_xor(mx, 2));
        mx = fmaxf(mx, __shfl_xor(mx, 4));
        mx = fmaxf(mx, __shfl_xor(mx, 8));
        const float mnew = fmaxf(mi[m][i], mx);
        const float alpha = __expf(mi[m][i] - mnew);
        float rs = 0.f;
#pragma unroll
        for (int h2 = 0; h2 < 4; ++h2) {
          const float e = __expf(s[h2][i] - mnew);
          p[h2][i] = e;
          rs += e;
        }
        rs += __shfl_xor(rs, 1);
        rs += __shfl_xor(rs, 2);
        rs += __shfl_xor(rs, 4);
        rs += __shfl_xor(rs, 8);
        li[m][i] = li[m][i] * alpha + rs;
        mi[m][i] = mnew;
#pragma unroll
        for (int dt = 0; dt < 4; ++dt) o[m][dt][i] *= alpha;
      }
      // ---- transpose P (D-layout -> A-fragment) through per-wave LDS ----
#pragma unroll
      for (int i = 0; i < 4; ++i)
#pragma unroll
        for (int h2 = 0; h2 < 4; ++h2)
          Plds[w][lg * 4 + i][h2 * 16 + lr] = f2b(p[h2][i]);
      bf16x8 ap0 = *(const bf16x8*)&Plds[w][lr][lg * 8];
      bf16x8 ap1 = *(const bf16x8*)&Plds[w][lr][32 + lg * 8];
      // ---- PV: O += P @ V, V^T fragments are vector loads ----
#pragma unroll
      for (int dt = 0; dt < 4; ++dt) {
        const ushort* vp = &VTb[(size_t)(dt * 16 + lr) * 2048 + k0 + lg * 8];
        bf16x8 bv0 = *(const bf16x8*)vp;
        bf16x8 bv1 = *(const bf16x8*)(vp + 32);
        o[m][dt] = MFMA16(ap0, bv0, o[m][dt]);
        o[m][dt] = MFMA16(ap1, bv1, o[m][dt]);
      }
    }
  }

#pragma unroll
  for (int m = 0; m < 2; ++m)
#pragma unroll
    for (int i = 0; i < 4; ++i) {
      const float inv = 1.f / li[m][i];
      const int t = q0w + m * 16 + lg * 4 + i;
#pragma unroll
      for (int dt = 0; dt < 4; ++dt)
        O[(size_t)(b * 2048 + t) * 1024 + h * 64 + dt * 16 + lr] = f2b(o[m][dt][i] * inv);
    }
}

extern "C" void kernel_launch(void* const* d_in, const int* in_sizes, int n_in,
                              void* d_out, int out_size, void* d_ws, size_t ws_size,
                              hipStream_t stream) {
  const float* x = (const float*)d_in[0];
  const float* w_qkv = (const float*)d_in[1];
  const float* b_qkv = (const float*)d_in[2];
  const float* w_proj = (const float*)d_in[3];
  const float* b_proj = (const float*)d_in[4];
  float* out = (float*)d_out;

  char* ws = (char*)d_ws;
  const size_t SZ_X = (size_t)8192 * 1024 * 2;        // 16.78 MB
  const size_t SZ_WQ = (size_t)3072 * 1024 * 2;       // 6.29 MB
  const size_t SZ_WP = (size_t)1024 * 1024 * 2;       // 2.10 MB
  ushort* xb = (ushort*)(ws);                         // x bf16; later reused as attn-out
  ushort* wqb = (ushort*)(ws + SZ_X);
  ushort* wpb = (ushort*)(ws + SZ_X + SZ_WQ);
  ushort* q_ws = (ushort*)(ws + SZ_X + SZ_WQ + SZ_WP);
  ushort* k_ws = q_ws + (size_t)8192 * 1024;
  ushort* v_ws = k_ws + (size_t)8192 * 1024;          // V^T [bh][64][2048]
  // total ws use: ~75.5 MB

  cvt_f32_bf16<<<8388608 / 4 / 256, 256, 0, stream>>>(x, xb, 8388608 / 4);
  cvt_f32_bf16<<<3145728 / 4 / 256, 256, 0, stream>>>(w_qkv, wqb, 3145728 / 4);
  cvt_f32_bf16<<<1048576 / 4 / 256, 256, 0, stream>>>(w_proj, wpb, 1048576 / 4);

  // QKV: M=8192 N=3072 K=1024, scatter epilogue (V transposed)
  gemm_bt<0><<<dim3(3072 / 128, 8192 / 128), 256, 0, stream>>>(
      xb, wqb, b_qkv, 8192, 3072, 1024, q_ws, k_ws, v_ws, nullptr);

  // attention, output (bf16 [B][T][C]) overwrites xb (GEMM1 already consumed it)
  attn_v2<<<16 * 64, 256, 0, stream>>>(q_ws, k_ws, v_ws, xb);

  // proj: M=8192 N=1024 K=1024, fp32 + bias to d_out
  gemm_bt<1><<<dim3(1024 / 128, 8192 / 128), 256, 0, stream>>>(
      xb, wpb, b_proj, 8192, 1024, 1024, nullptr, nullptr, nullptr, out);
}

// Round 3
// 383.327 us; speedup vs baseline: 1.0493x; 1.0493x over previous
//
#include <hip/hip_runtime.h>
#include <hip/hip_bf16.h>
#include <cstdint>

typedef __attribute__((ext_vector_type(8))) short bf16x8;
typedef __attribute__((ext_vector_type(4))) float f32x4;

#define MFMA16(a, b, c) __builtin_amdgcn_mfma_f32_16x16x32_bf16(a, b, c, 0, 0, 0)

typedef __attribute__((address_space(1))) uint32_t as1_u32;
typedef __attribute__((address_space(3))) uint32_t as3_u32;
static __device__ __forceinline__ void gload16(const void* g, void* l) {
  __builtin_amdgcn_global_load_lds((as1_u32*)g, (as3_u32*)l, 16, 0, 0);
}

static __device__ __forceinline__ ushort f2b(float f) {
  union { float f; uint32_t u; } v; v.f = f;
  uint32_t u = v.u;
  uint32_t r = (u + 0x7FFFu + ((u >> 16) & 1u)) >> 16;
  return (ushort)r;
}

// 0.125 (1/sqrt(64)) * log2(e): folded into Q so attn uses exp2 directly
#define QSCALE 0.1803368782f

// ---------- fp32 -> bf16 convert (n4 = n/4 float4 chunks) ----------
__global__ void cvt_f32_bf16(const float* __restrict__ in, ushort* __restrict__ out, int n4) {
  int i = blockIdx.x * blockDim.x + threadIdx.x;
  if (i >= n4) return;
  const float4 v = ((const float4*)in)[i];
  ushort4 o;
  o.x = f2b(v.x); o.y = f2b(v.y); o.z = f2b(v.z); o.w = f2b(v.w);
  ((ushort4*)out)[i] = o;
}

// ---------- GEMM: C[m][n] = sum_k A[m][k] * W[n][k] + bias[n] ----------
// m97 structure: global_load_lds width-16 staging into LINEAR LDS.
// EPI=0: scatter q (pre-scaled by QSCALE), k -> [B*H][T][64]; v -> V^T [B*H][64][T]
// EPI=1: fp32 out [M][N]
template<int EPI>
__global__ __launch_bounds__(256) void gemm_bt(
    const ushort* __restrict__ A,    // [M][K] bf16
    const ushort* __restrict__ W,    // [N][K] bf16
    const float* __restrict__ bias,  // [N]
    int M, int N, int K,
    ushort* __restrict__ q_ws, ushort* __restrict__ k_ws, ushort* __restrict__ v_ws,
    float* __restrict__ out) {
  __shared__ ushort As[128 * 64];  // linear: global_load_lds needs contiguous dest
  __shared__ ushort Bs[128 * 64];
  const int tid = threadIdx.x;
  const int m0 = blockIdx.y * 128, n0 = blockIdx.x * 128;
  const int lane = tid & 63, w = tid >> 6;
  const int lr = lane & 15, lg = lane >> 4;
  const int wm = (w >> 1) * 64, wn = (w & 1) * 64;
  f32x4 acc[4][4] = {};

  for (int k0 = 0; k0 < K; k0 += 64) {
    __syncthreads();
#pragma unroll
    for (int it = 0; it < 4; ++it) {
      const int chunk = it * 256 + tid;  // wave-contiguous: it*256 + w*64 + lane
      const int r = chunk >> 3;          // 0..127
      const int c = (chunk & 7) * 8;     // 0..56
      gload16(&A[(size_t)(m0 + r) * K + k0 + c], &As[chunk * 8]);
      gload16(&W[(size_t)(n0 + r) * K + k0 + c], &Bs[chunk * 8]);
    }
    __syncthreads();  // drains vmcnt: LDS data ready
#pragma unroll
    for (int kk = 0; kk < 2; ++kk) {
      bf16x8 a[4], b[4];
#pragma unroll
      for (int mi = 0; mi < 4; ++mi)
        a[mi] = *(const bf16x8*)&As[(wm + mi * 16 + lr) * 64 + kk * 32 + lg * 8];
#pragma unroll
      for (int ni = 0; ni < 4; ++ni)
        b[ni] = *(const bf16x8*)&Bs[(wn + ni * 16 + lr) * 64 + kk * 32 + lg * 8];
#pragma unroll
      for (int mi = 0; mi < 4; ++mi)
#pragma unroll
        for (int ni = 0; ni < 4; ++ni)
          acc[mi][ni] = MFMA16(a[mi], b[ni], acc[mi][ni]);
    }
  }

#pragma unroll
  for (int mi = 0; mi < 4; ++mi) {
#pragma unroll
    for (int ni = 0; ni < 4; ++ni) {
      const int rowb = m0 + wm + mi * 16 + lg * 4;  // C/D: row=(lane>>4)*4+reg, col=lane&15
      const int col = n0 + wn + ni * 16 + lr;
      float v[4];
#pragma unroll
      for (int i = 0; i < 4; ++i) v[i] = acc[mi][ni][i] + bias[col];
      if (EPI == 0) {
        const int sel = col >> 10;        // uniform per block (n0 multiple of 128)
        const int rem = col & 1023;
        const int h = rem >> 6, d = rem & 63;
        const int bb = rowb >> 11, t0 = rowb & 2047;
        if (sel == 2) {
          // V^T: [bh][d][t] — 4 regs are t-contiguous -> packed 8B store
          ushort4 st;
          st.x = f2b(v[0]); st.y = f2b(v[1]); st.z = f2b(v[2]); st.w = f2b(v[3]);
          *(ushort4*)&v_ws[((size_t)(bb * 16 + h) * 64 + d) * 2048 + t0] = st;
        } else if (sel == 0) {
#pragma unroll
          for (int i = 0; i < 4; ++i)
            q_ws[((size_t)(bb * 16 + h) * 2048 + t0 + i) * 64 + d] = f2b(v[i] * QSCALE);
        } else {
#pragma unroll
          for (int i = 0; i < 4; ++i)
            k_ws[((size_t)(bb * 16 + h) * 2048 + t0 + i) * 64 + d] = f2b(v[i]);
        }
      } else {
#pragma unroll
        for (int i = 0; i < 4; ++i)
          out[(size_t)(rowb + i) * N + col] = v[i];
      }
    }
  }
}

// ---------- causal flash attention v3: max-free softmax, MFMA row-sum ----------
// wave = 32 q rows, KVBLK=64; 2 independent waves/block; heavy-qblk-first order
__global__ __launch_bounds__(128) void attn_v3(
    const ushort* __restrict__ Q, const ushort* __restrict__ K,
    const ushort* __restrict__ VT, ushort* __restrict__ O /* [B][T][C] bf16 */) {
  const int blk = blockIdx.x;
  const int qblk = 15 - (blk >> 7);  // heavy strips dispatch first (LPT)
  const int rr = blk & 127;
  const int bh = rr >> 1;
  const int half = rr & 1;
  const int w = threadIdx.x >> 6;
  const int lane = threadIdx.x & 63;
  const int lr = lane & 15, lg = lane >> 4;
  const int q0w = qblk * 128 + half * 64 + w * 32;
  const int bb = bh >> 4, h = bh & 15;
  const size_t base = (size_t)bh * 2048 * 64;
  const ushort* Qb = Q + base;
  const ushort* Kb = K + base;
  const ushort* VTb = VT + base;  // [64][2048]

  __shared__ ushort Plds[2][16][72];  // per-wave region, padded

  const bf16x8 vone = {0x3F80, 0x3F80, 0x3F80, 0x3F80, 0x3F80, 0x3F80, 0x3F80, 0x3F80};

  bf16x8 aq[2][2];
#pragma unroll
  for (int m = 0; m < 2; ++m)
#pragma unroll
    for (int kk = 0; kk < 2; ++kk)
      aq[m][kk] = *(const bf16x8*)&Qb[(size_t)(q0w + m * 16 + lr) * 64 + kk * 32 + lg * 8];

  f32x4 o[2][4] = {};
  f32x4 lacc[2] = {};

  const int ktiles = ((q0w + 31) >> 6) + 1;
  for (int kt = 0; kt < ktiles; ++kt) {
    const int k0 = kt << 6;
#pragma unroll
    for (int m = 0; m < 2; ++m) {
      const int qm = q0w + m * 16;
      // ---- QK^T: S[16 q][64 k], scale already folded into Q ----
      f32x4 s[4];
#pragma unroll
      for (int h2 = 0; h2 < 4; ++h2) {
        const ushort* kp = &Kb[(size_t)(k0 + h2 * 16 + lr) * 64 + lg * 8];
        bf16x8 bk0 = *(const bf16x8*)kp;
        bf16x8 bk1 = *(const bf16x8*)(kp + 32);
        f32x4 t = {};
        t = MFMA16(aq[m][0], bk0, t);
        t = MFMA16(aq[m][1], bk1, t);
        s[h2] = t;
      }
      // ---- causal mask (diagonal tiles only) ----
      if (k0 + 63 > qm) {
#pragma unroll
        for (int i = 0; i < 4; ++i) {
          const int row = qm + lg * 4 + i;
#pragma unroll
          for (int h2 = 0; h2 < 4; ++h2) {
            const int col = k0 + h2 * 16 + lr;
            s[h2][i] = (col <= row) ? s[h2][i] : -INFINITY;
          }
        }
      }
      // ---- max-free softmax numerator: p = 2^s (masked -> 0) ----
#pragma unroll
      for (int i = 0; i < 4; ++i)
#pragma unroll
        for (int h2 = 0; h2 < 4; ++h2)
          Plds[w][lg * 4 + i][h2 * 16 + lr] = f2b(exp2f(s[h2][i]));
      bf16x8 ap0 = *(const bf16x8*)&Plds[w][lr][lg * 8];
      bf16x8 ap1 = *(const bf16x8*)&Plds[w][lr][32 + lg * 8];
      // ---- row-sum l via ones-MFMA (replaces shuffle reduction) ----
      lacc[m] = MFMA16(ap0, vone, lacc[m]);
      lacc[m] = MFMA16(ap1, vone, lacc[m]);
      // ---- PV: O += P @ V ----
#pragma unroll
      for (int dt = 0; dt < 4; ++dt) {
        const ushort* vp = &VTb[(size_t)(dt * 16 + lr) * 2048 + k0 + lg * 8];
        bf16x8 bv0 = *(const bf16x8*)vp;
        bf16x8 bv1 = *(const bf16x8*)(vp + 32);
        o[m][dt] = MFMA16(ap0, bv0, o[m][dt]);
        o[m][dt] = MFMA16(ap1, bv1, o[m][dt]);
      }
    }
  }

#pragma unroll
  for (int m = 0; m < 2; ++m)
#pragma unroll
    for (int i = 0; i < 4; ++i) {
      const float inv = 1.f / lacc[m][i];
      const int t = q0w + m * 16 + lg * 4 + i;
#pragma unroll
      for (int dt = 0; dt < 4; ++dt)
        O[(size_t)(bb * 2048 + t) * 1024 + h * 64 + dt * 16 + lr] = f2b(o[m][dt][i] * inv);
    }
}

extern "C" void kernel_launch(void* const* d_in, const int* in_sizes, int n_in,
                              void* d_out, int out_size, void* d_ws, size_t ws_size,
                              hipStream_t stream) {
  const float* x = (const float*)d_in[0];
  const float* w_qkv = (const float*)d_in[1];
  const float* b_qkv = (const float*)d_in[2];
  const float* w_proj = (const float*)d_in[3];
  const float* b_proj = (const float*)d_in[4];
  float* out = (float*)d_out;

  char* ws = (char*)d_ws;
  const size_t SZ_X = (size_t)8192 * 1024 * 2;        // 16.78 MB
  const size_t SZ_WQ = (size_t)3072 * 1024 * 2;       // 6.29 MB
  const size_t SZ_WP = (size_t)1024 * 1024 * 2;       // 2.10 MB
  ushort* xb = (ushort*)(ws);                         // x bf16; later reused as attn-out
  ushort* wqb = (ushort*)(ws + SZ_X);
  ushort* wpb = (ushort*)(ws + SZ_X + SZ_WQ);
  ushort* q_ws = (ushort*)(ws + SZ_X + SZ_WQ + SZ_WP);
  ushort* k_ws = q_ws + (size_t)8192 * 1024;
  ushort* v_ws = k_ws + (size_t)8192 * 1024;          // V^T [bh][64][2048]
  // total ws use: ~75.5 MB

  cvt_f32_bf16<<<8388608 / 4 / 256, 256, 0, stream>>>(x, xb, 8388608 / 4);
  cvt_f32_bf16<<<3145728 / 4 / 256, 256, 0, stream>>>(w_qkv, wqb, 3145728 / 4);
  cvt_f32_bf16<<<1048576 / 4 / 256, 256, 0, stream>>>(w_proj, wpb, 1048576 / 4);

  // QKV: M=8192 N=3072 K=1024, scatter epilogue (Q pre-scaled, V transposed)
  gemm_bt<0><<<dim3(3072 / 128, 8192 / 128), 256, 0, stream>>>(
      xb, wqb, b_qkv, 8192, 3072, 1024, q_ws, k_ws, v_ws, nullptr);

  // attention, output (bf16 [B][T][C]) overwrites xb (GEMM1 already consumed it)
  attn_v3<<<2048, 128, 0, stream>>>(q_ws, k_ws, v_ws, xb);

  // proj: M=8192 N=1024 K=1024, fp32 + bias to d_out
  gemm_bt<1><<<dim3(1024 / 128, 8192 / 128), 256, 0, stream>>>(
      xb, wpb, b_proj, 8192, 1024, 1024, nullptr, nullptr, nullptr, out);
}

// Round 4
// 218.284 us; speedup vs baseline: 1.8427x; 1.7561x over previous
//
#include <hip/hip_runtime.h>
#include <hip/hip_bf16.h>
#include <cstdint>

typedef __attribute__((ext_vector_type(8))) short bf16x8;
typedef __attribute__((ext_vector_type(4))) float f32x4;

#define MFMA16(a, b, c) __builtin_amdgcn_mfma_f32_16x16x32_bf16(a, b, c, 0, 0, 0)

typedef __attribute__((address_space(1))) uint32_t as1_u32;
typedef __attribute__((address_space(3))) uint32_t as3_u32;
static __device__ __forceinline__ void gload16(const void* g, void* l) {
  __builtin_amdgcn_global_load_lds((as1_u32*)g, (as3_u32*)l, 16, 0, 0);
}

static __device__ __forceinline__ ushort f2b(float f) {
  union { float f; uint32_t u; } v; v.f = f;
  uint32_t u = v.u;
  uint32_t r = (u + 0x7FFFu + ((u >> 16) & 1u)) >> 16;
  return (ushort)r;
}

// 0.125 (1/sqrt(64)) * log2(e): folded into Q so attn uses exp2 directly
#define QSCALE 0.1803368782f

// ---------- fp32 -> bf16 convert (n4 = n/4 float4 chunks) ----------
__global__ void cvt_f32_bf16(const float* __restrict__ in, ushort* __restrict__ out, int n4) {
  int i = blockIdx.x * blockDim.x + threadIdx.x;
  if (i >= n4) return;
  const float4 v = ((const float4*)in)[i];
  ushort4 o;
  o.x = f2b(v.x); o.y = f2b(v.y); o.z = f2b(v.z); o.w = f2b(v.w);
  ((ushort4*)out)[i] = o;
}

// ---------- GEMM: C[m][n] = sum_k A[m][k] * W[n][k] + bias[n] ----------
// m97 structure: global_load_lds width-16 staging into LINEAR LDS.
// EPI=0: scatter q (pre-scaled by QSCALE), k -> [B*H][T][64]; v -> V^T [B*H][64][T]
// EPI=1: fp32 out [M][N]
template<int EPI>
__global__ __launch_bounds__(256) void gemm_bt(
    const ushort* __restrict__ A,    // [M][K] bf16
    const ushort* __restrict__ W,    // [N][K] bf16
    const float* __restrict__ bias,  // [N]
    int M, int N, int K,
    ushort* __restrict__ q_ws, ushort* __restrict__ k_ws, ushort* __restrict__ v_ws,
    float* __restrict__ out) {
  __shared__ ushort As[128 * 64];  // linear: global_load_lds needs contiguous dest
  __shared__ ushort Bs[128 * 64];
  const int tid = threadIdx.x;
  const int m0 = blockIdx.y * 128, n0 = blockIdx.x * 128;
  const int lane = tid & 63, w = tid >> 6;
  const int lr = lane & 15, lg = lane >> 4;
  const int wm = (w >> 1) * 64, wn = (w & 1) * 64;
  f32x4 acc[4][4] = {};

  for (int k0 = 0; k0 < K; k0 += 64) {
    __syncthreads();
#pragma unroll
    for (int it = 0; it < 4; ++it) {
      const int chunk = it * 256 + tid;  // wave-contiguous: it*256 + w*64 + lane
      const int r = chunk >> 3;          // 0..127
      const int c = (chunk & 7) * 8;     // 0..56
      gload16(&A[(size_t)(m0 + r) * K + k0 + c], &As[chunk * 8]);
      gload16(&W[(size_t)(n0 + r) * K + k0 + c], &Bs[chunk * 8]);
    }
    __syncthreads();  // drains vmcnt: LDS data ready
#pragma unroll
    for (int kk = 0; kk < 2; ++kk) {
      bf16x8 a[4], b[4];
#pragma unroll
      for (int mi = 0; mi < 4; ++mi)
        a[mi] = *(const bf16x8*)&As[(wm + mi * 16 + lr) * 64 + kk * 32 + lg * 8];
#pragma unroll
      for (int ni = 0; ni < 4; ++ni)
        b[ni] = *(const bf16x8*)&Bs[(wn + ni * 16 + lr) * 64 + kk * 32 + lg * 8];
#pragma unroll
      for (int mi = 0; mi < 4; ++mi)
#pragma unroll
        for (int ni = 0; ni < 4; ++ni)
          acc[mi][ni] = MFMA16(a[mi], b[ni], acc[mi][ni]);
    }
  }

#pragma unroll
  for (int mi = 0; mi < 4; ++mi) {
#pragma unroll
    for (int ni = 0; ni < 4; ++ni) {
      const int rowb = m0 + wm + mi * 16 + lg * 4;  // C/D: row=(lane>>4)*4+reg, col=lane&15
      const int col = n0 + wn + ni * 16 + lr;
      float v[4];
#pragma unroll
      for (int i = 0; i < 4; ++i) v[i] = acc[mi][ni][i] + bias[col];
      if (EPI == 0) {
        const int sel = col >> 10;        // uniform per block (n0 multiple of 128)
        const int rem = col & 1023;
        const int h = rem >> 6, d = rem & 63;
        const int bb = rowb >> 11, t0 = rowb & 2047;
        if (sel == 2) {
          // V^T: [bh][d][t] — 4 regs are t-contiguous -> packed 8B store
          ushort4 st;
          st.x = f2b(v[0]); st.y = f2b(v[1]); st.z = f2b(v[2]); st.w = f2b(v[3]);
          *(ushort4*)&v_ws[((size_t)(bb * 16 + h) * 64 + d) * 2048 + t0] = st;
        } else if (sel == 0) {
#pragma unroll
          for (int i = 0; i < 4; ++i)
            q_ws[((size_t)(bb * 16 + h) * 2048 + t0 + i) * 64 + d] = f2b(v[i] * QSCALE);
        } else {
#pragma unroll
          for (int i = 0; i < 4; ++i)
            k_ws[((size_t)(bb * 16 + h) * 2048 + t0 + i) * 64 + d] = f2b(v[i]);
        }
      } else {
#pragma unroll
        for (int i = 0; i < 4; ++i)
          out[(size_t)(rowb + i) * N + col] = v[i];
      }
    }
  }
}

// ---------- causal flash attention v4 ----------
// block = 4 waves = 128 q rows; processes TWO strips (15-pr, pr) -> 34 tiles/block.
// K/V tiles staged in LDS via global_load_lds (XOR-swizzled src), double-buffered.
__global__ __launch_bounds__(256) void attn_v4(
    const ushort* __restrict__ Q, const ushort* __restrict__ K,
    const ushort* __restrict__ VT, ushort* __restrict__ O /* [B][T][C] bf16 */) {
  const int bh = blockIdx.x >> 3;
  const int pr = blockIdx.x & 7;
  const int tid = threadIdx.x;
  const int w = tid >> 6, lane = tid & 63;
  const int lr = lane & 15, lg = lane >> 4;
  const int bb = bh >> 4, h = bh & 15;
  const size_t base = (size_t)bh * 2048 * 64;
  const ushort* Qb = Q + base;
  const ushort* Kb = K + base;
  const ushort* VTb = VT + base;  // [64][2048]

  __shared__ ushort Ks[2][64 * 64];   // 8KB x2, linear, col-chunk swizzled
  __shared__ ushort Vs[2][64 * 64];
  __shared__ ushort Plds[4][16][72];  // per-wave P transpose

  const bf16x8 vone = {0x3F80, 0x3F80, 0x3F80, 0x3F80, 0x3F80, 0x3F80, 0x3F80, 0x3F80};

#pragma unroll 1
  for (int ph = 0; ph < 2; ++ph) {
    const int s = ph ? pr : 15 - pr;   // strip pairing: 34 tiles total per block
    const int q0w = s * 128 + w * 32;
    const int nt = 2 * s + 2;

    bf16x8 aq[2][2];
#pragma unroll
    for (int m = 0; m < 2; ++m)
#pragma unroll
      for (int kk = 0; kk < 2; ++kk)
        aq[m][kk] = *(const bf16x8*)&Qb[(size_t)(q0w + m * 16 + lr) * 64 + kk * 32 + lg * 8];

    f32x4 o[2][4] = {};
    f32x4 lacc[2] = {};

    // prologue: stage tile 0 into buf 0
#pragma unroll
    for (int i = 0; i < 2; ++i) {
      const int ch = i * 256 + tid;  // 0..511
      const int r = ch >> 3;         // 0..63
      const int csw = ((ch & 7) ^ (r & 7)) * 8;  // inverse-swizzled source col
      gload16(&Kb[(size_t)r * 64 + csw], &Ks[0][ch * 8]);
      gload16(&VTb[(size_t)r * 2048 + csw], &Vs[0][ch * 8]);
    }
    __syncthreads();

    for (int kt = 0; kt < nt; ++kt) {
      const int cur = kt & 1;
      if (kt + 1 < nt) {  // prefetch next tile into other buffer
        const ushort* Kt = Kb + (size_t)(kt + 1) * 64 * 64;
        const ushort* Vt = VTb + (kt + 1) * 64;
#pragma unroll
        for (int i = 0; i < 2; ++i) {
          const int ch = i * 256 + tid;
          const int r = ch >> 3;
          const int csw = ((ch & 7) ^ (r & 7)) * 8;
          gload16(&Kt[(size_t)r * 64 + csw], &Ks[cur ^ 1][ch * 8]);
          gload16(&Vt[(size_t)r * 2048 + csw], &Vs[cur ^ 1][ch * 8]);
        }
      }
      const int k0 = kt << 6;
      const ushort* Ksc = Ks[cur];
      const ushort* Vsc = Vs[cur];
#pragma unroll
      for (int m = 0; m < 2; ++m) {
        const int qm = q0w + m * 16;
        // ---- QK^T from LDS (swizzled read) ----
        f32x4 sv[4];
#pragma unroll
        for (int h2 = 0; h2 < 4; ++h2) {
          const int row = h2 * 16 + lr;
          const int rx = row & 7;
          bf16x8 bk0 = *(const bf16x8*)&Ksc[row * 64 + ((lg ^ rx) * 8)];
          bf16x8 bk1 = *(const bf16x8*)&Ksc[row * 64 + (((lg + 4) ^ rx) * 8)];
          f32x4 t = {};
          t = MFMA16(aq[m][0], bk0, t);
          t = MFMA16(aq[m][1], bk1, t);
          sv[h2] = t;
        }
        // ---- causal mask (diagonal/overshoot tiles) ----
        if (k0 + 63 > qm) {
#pragma unroll
          for (int i = 0; i < 4; ++i) {
            const int row = qm + lg * 4 + i;
#pragma unroll
            for (int h2 = 0; h2 < 4; ++h2) {
              const int col = k0 + h2 * 16 + lr;
              sv[h2][i] = (col <= row) ? sv[h2][i] : -INFINITY;
            }
          }
        }
        // ---- max-free softmax numerator: p = 2^s ----
#pragma unroll
        for (int i = 0; i < 4; ++i)
#pragma unroll
          for (int h2 = 0; h2 < 4; ++h2)
            Plds[w][lg * 4 + i][h2 * 16 + lr] = f2b(exp2f(sv[h2][i]));
        bf16x8 ap0 = *(const bf16x8*)&Plds[w][lr][lg * 8];
        bf16x8 ap1 = *(const bf16x8*)&Plds[w][lr][32 + lg * 8];
        // ---- row-sum via ones-MFMA ----
        lacc[m] = MFMA16(ap0, vone, lacc[m]);
        lacc[m] = MFMA16(ap1, vone, lacc[m]);
        // ---- PV from LDS (swizzled read) ----
#pragma unroll
        for (int dt = 0; dt < 4; ++dt) {
          const int row = dt * 16 + lr;
          const int rx = row & 7;
          bf16x8 bv0 = *(const bf16x8*)&Vsc[row * 64 + ((lg ^ rx) * 8)];
          bf16x8 bv1 = *(const bf16x8*)&Vsc[row * 64 + (((lg + 4) ^ rx) * 8)];
          o[m][dt] = MFMA16(ap0, bv0, o[m][dt]);
          o[m][dt] = MFMA16(ap1, bv1, o[m][dt]);
        }
      }
      __syncthreads();  // drains staging vmcnt; protects buf reuse
    }

#pragma unroll
    for (int m = 0; m < 2; ++m)
#pragma unroll
      for (int i = 0; i < 4; ++i) {
        const float inv = 1.f / lacc[m][i];
        const int t = q0w + m * 16 + lg * 4 + i;
#pragma unroll
        for (int dt = 0; dt < 4; ++dt)
          O[(size_t)(bb * 2048 + t) * 1024 + h * 64 + dt * 16 + lr] = f2b(o[m][dt][i] * inv);
      }
  }
}

extern "C" void kernel_launch(void* const* d_in, const int* in_sizes, int n_in,
                              void* d_out, int out_size, void* d_ws, size_t ws_size,
                              hipStream_t stream) {
  const float* x = (const float*)d_in[0];
  const float* w_qkv = (const float*)d_in[1];
  const float* b_qkv = (const float*)d_in[2];
  const float* w_proj = (const float*)d_in[3];
  const float* b_proj = (const float*)d_in[4];
  float* out = (float*)d_out;

  char* ws = (char*)d_ws;
  const size_t SZ_X = (size_t)8192 * 1024 * 2;        // 16.78 MB
  const size_t SZ_WQ = (size_t)3072 * 1024 * 2;       // 6.29 MB
  const size_t SZ_WP = (size_t)1024 * 1024 * 2;       // 2.10 MB
  ushort* xb = (ushort*)(ws);                         // x bf16; later reused as attn-out
  ushort* wqb = (ushort*)(ws + SZ_X);
  ushort* wpb = (ushort*)(ws + SZ_X + SZ_WQ);
  ushort* q_ws = (ushort*)(ws + SZ_X + SZ_WQ + SZ_WP);
  ushort* k_ws = q_ws + (size_t)8192 * 1024;
  ushort* v_ws = k_ws + (size_t)8192 * 1024;          // V^T [bh][64][2048]
  // total ws use: ~75.5 MB

  cvt_f32_bf16<<<8388608 / 4 / 256, 256, 0, stream>>>(x, xb, 8388608 / 4);
  cvt_f32_bf16<<<3145728 / 4 / 256, 256, 0, stream>>>(w_qkv, wqb, 3145728 / 4);
  cvt_f32_bf16<<<1048576 / 4 / 256, 256, 0, stream>>>(w_proj, wpb, 1048576 / 4);

  // QKV: M=8192 N=3072 K=1024, scatter epilogue (Q pre-scaled, V transposed)
  gemm_bt<0><<<dim3(3072 / 128, 8192 / 128), 256, 0, stream>>>(
      xb, wqb, b_qkv, 8192, 3072, 1024, q_ws, k_ws, v_ws, nullptr);

  // attention: 64 bh x 8 strip-pairs, 34 tiles per block (balanced)
  attn_v4<<<512, 256, 0, stream>>>(q_ws, k_ws, v_ws, xb);

  // proj: M=8192 N=1024 K=1024, fp32 + bias to d_out
  gemm_bt<1><<<dim3(1024 / 128, 8192 / 128), 256, 0, stream>>>(
      xb, wpb, b_proj, 8192, 1024, 1024, nullptr, nullptr, nullptr, out);
}

// Round 5
// 187.408 us; speedup vs baseline: 2.1462x; 1.1648x over previous
//
#include <hip/hip_runtime.h>
#include <hip/hip_bf16.h>
#include <cstdint>

typedef __attribute__((ext_vector_type(8))) short bf16x8;
typedef __attribute__((ext_vector_type(4))) float f32x4;
typedef __attribute__((ext_vector_type(16))) float f32x16;

#define MFMA16(a, b, c) __builtin_amdgcn_mfma_f32_16x16x32_bf16(a, b, c, 0, 0, 0)
#define MFMA32(a, b, c) __builtin_amdgcn_mfma_f32_32x32x16_bf16(a, b, c, 0, 0, 0)

typedef __attribute__((address_space(1))) uint32_t as1_u32;
typedef __attribute__((address_space(3))) uint32_t as3_u32;
static __device__ __forceinline__ void gload16(const void* g, void* l) {
  __builtin_amdgcn_global_load_lds((as1_u32*)g, (as3_u32*)l, 16, 0, 0);
}

static __device__ __forceinline__ ushort f2b(float f) {
  union { float f; uint32_t u; } v; v.f = f;
  uint32_t u = v.u;
  uint32_t r = (u + 0x7FFFu + ((u >> 16) & 1u)) >> 16;
  return (ushort)r;
}

// D.lo16 = bf16(a), D.hi16 = bf16(b)  (RNE)
static __device__ __forceinline__ uint32_t cvtpk(float a, float b) {
  uint32_t r;
  asm("v_cvt_pk_bf16_f32 %0, %1, %2" : "=v"(r) : "v"(a), "v"(b));
  return r;
}
// ISA: for i<32: tmp=a[i+32]; a[i+32]=b[i]; b[i]=tmp  ->  a'={a.lo,b.lo}, b'={a.hi,b.hi}
static __device__ __forceinline__ void plswap(uint32_t& a, uint32_t& b) {
  asm volatile("v_permlane32_swap_b32 %0, %1" : "+v"(a), "+v"(b));
}

// 0.125 (1/sqrt(64)) * log2(e): folded into Q so attn uses exp2 directly
#define QSCALE 0.1803368782f

// ---------- fp32 -> bf16 convert (n4 = n/4 float4 chunks) ----------
__global__ void cvt_f32_bf16(const float* __restrict__ in, ushort* __restrict__ out, int n4) {
  int i = blockIdx.x * blockDim.x + threadIdx.x;
  if (i >= n4) return;
  const float4 v = ((const float4*)in)[i];
  ushort4 o;
  o.x = f2b(v.x); o.y = f2b(v.y); o.z = f2b(v.z); o.w = f2b(v.w);
  ((ushort4*)out)[i] = o;
}

// ---------- GEMM: C[m][n] = sum_k A[m][k] * W[n][k] + bias[n] ----------
// EPI=0: scatter q (pre-scaled by QSCALE), k -> [B*H][T][64]; v -> V^T [B*H][64][T]
// EPI=1: fp32 out [M][N]
template<int EPI>
__global__ __launch_bounds__(256) void gemm_bt(
    const ushort* __restrict__ A,    // [M][K] bf16
    const ushort* __restrict__ W,    // [N][K] bf16
    const float* __restrict__ bias,  // [N]
    int M, int N, int K,
    ushort* __restrict__ q_ws, ushort* __restrict__ k_ws, ushort* __restrict__ v_ws,
    float* __restrict__ out) {
  __shared__ ushort As[128 * 64];  // linear: global_load_lds needs contiguous dest
  __shared__ ushort Bs[128 * 64];
  const int tid = threadIdx.x;
  const int m0 = blockIdx.y * 128, n0 = blockIdx.x * 128;
  const int lane = tid & 63, w = tid >> 6;
  const int lr = lane & 15, lg = lane >> 4;
  const int wm = (w >> 1) * 64, wn = (w & 1) * 64;
  f32x4 acc[4][4] = {};

  for (int k0 = 0; k0 < K; k0 += 64) {
    __syncthreads();
#pragma unroll
    for (int it = 0; it < 4; ++it) {
      const int chunk = it * 256 + tid;  // wave-contiguous
      const int r = chunk >> 3;          // 0..127
      const int c = (chunk & 7) * 8;     // 0..56
      gload16(&A[(size_t)(m0 + r) * K + k0 + c], &As[chunk * 8]);
      gload16(&W[(size_t)(n0 + r) * K + k0 + c], &Bs[chunk * 8]);
    }
    __syncthreads();  // drains vmcnt: LDS data ready
#pragma unroll
    for (int kk = 0; kk < 2; ++kk) {
      bf16x8 a[4], b[4];
#pragma unroll
      for (int mi = 0; mi < 4; ++mi)
        a[mi] = *(const bf16x8*)&As[(wm + mi * 16 + lr) * 64 + kk * 32 + lg * 8];
#pragma unroll
      for (int ni = 0; ni < 4; ++ni)
        b[ni] = *(const bf16x8*)&Bs[(wn + ni * 16 + lr) * 64 + kk * 32 + lg * 8];
#pragma unroll
      for (int mi = 0; mi < 4; ++mi)
#pragma unroll
        for (int ni = 0; ni < 4; ++ni)
          acc[mi][ni] = MFMA16(a[mi], b[ni], acc[mi][ni]);
    }
  }

#pragma unroll
  for (int mi = 0; mi < 4; ++mi) {
#pragma unroll
    for (int ni = 0; ni < 4; ++ni) {
      const int rowb = m0 + wm + mi * 16 + lg * 4;  // C/D: row=(lane>>4)*4+reg, col=lane&15
      const int col = n0 + wn + ni * 16 + lr;
      float v[4];
#pragma unroll
      for (int i = 0; i < 4; ++i) v[i] = acc[mi][ni][i] + bias[col];
      if (EPI == 0) {
        const int sel = col >> 10;        // uniform per block
        const int rem = col & 1023;
        const int h = rem >> 6, d = rem & 63;
        const int bb = rowb >> 11, t0 = rowb & 2047;
        if (sel == 2) {
          ushort4 st;
          st.x = f2b(v[0]); st.y = f2b(v[1]); st.z = f2b(v[2]); st.w = f2b(v[3]);
          *(ushort4*)&v_ws[((size_t)(bb * 16 + h) * 64 + d) * 2048 + t0] = st;
        } else if (sel == 0) {
#pragma unroll
          for (int i = 0; i < 4; ++i)
            q_ws[((size_t)(bb * 16 + h) * 2048 + t0 + i) * 64 + d] = f2b(v[i] * QSCALE);
        } else {
#pragma unroll
          for (int i = 0; i < 4; ++i)
            k_ws[((size_t)(bb * 16 + h) * 2048 + t0 + i) * 64 + d] = f2b(v[i]);
        }
      } else {
#pragma unroll
        for (int i = 0; i < 4; ++i)
          out[(size_t)(rowb + i) * N + col] = v[i];
      }
    }
  }
}

// ---------- causal flash attention v5: swapped QK^T, in-register softmax ----------
// block = 4 waves x 32 q rows = 128 q (one strip); two strips (15-pr, pr) per block.
// K/V LDS-staged (XOR-swizzled, double-buffered). bh = blk&63 -> same-bh on same XCD.
__global__ __launch_bounds__(256) void attn_v5(
    const ushort* __restrict__ Q, const ushort* __restrict__ K,
    const ushort* __restrict__ VT, ushort* __restrict__ O /* [B][T][C] bf16 */) {
  const int blk = blockIdx.x;
  const int bh = blk & 63;   // mod-8-equal ids land on one XCD: K/V L2-resident
  const int pr = blk >> 6;   // 0..7
  const int tid = threadIdx.x;
  const int w = tid >> 6, lane = tid & 63;
  const int l31 = lane & 31, l5 = lane >> 5;
  const int bb = bh >> 4, h = bh & 15;
  const size_t base = (size_t)bh * 2048 * 64;
  const ushort* Qb = Q + base;
  const ushort* Kb = K + base;
  const ushort* VTb = VT + base;  // [64][2048]

  __shared__ ushort Ks[2][64 * 64];  // [k-row][d], chunk-swizzled
  __shared__ ushort Vs[2][64 * 64];  // [d-row][k], chunk-swizzled
  __shared__ float l_lds[4][32];

#define STAGE(buf, kt_)                                              \
  do {                                                               \
    const ushort* Kt = Kb + (size_t)(kt_) * 64 * 64;                 \
    const ushort* Vt = VTb + (kt_) * 64;                             \
    _Pragma("unroll") for (int i_ = 0; i_ < 2; ++i_) {               \
      const int ch = i_ * 256 + tid;                                 \
      const int r = ch >> 3;                                         \
      const int csw = ((ch & 7) ^ (r & 7)) * 8;                      \
      gload16(&Kt[(size_t)r * 64 + csw], &Ks[buf][ch * 8]);          \
      gload16(&Vt[(size_t)r * 2048 + csw], &Vs[buf][ch * 8]);        \
    }                                                                \
  } while (0)

#pragma unroll 1
  for (int ph = 0; ph < 2; ++ph) {
    const int s = ph ? pr : 15 - pr;  // strip pairing: 34 tiles/block total
    const int q0w = s * 128 + w * 32;
    const int nt = 2 * s + 2;
    const int qlane = q0w + l31;  // this lane's q-column in S^T

    // Q as B-fragments: lane holds Q[qlane][dblk*16 + l5*8 + j]
    bf16x8 qf[4];
#pragma unroll
    for (int dblk = 0; dblk < 4; ++dblk)
      qf[dblk] = *(const bf16x8*)&Qb[(size_t)qlane * 64 + dblk * 16 + l5 * 8];

    f32x16 o0 = {}, o1 = {};
    float lsum = 0.f;

    STAGE(0, 0);
    __syncthreads();

    for (int kt = 0; kt < nt; ++kt) {
      const int cur = kt & 1;
      if (kt + 1 < nt) STAGE(cur ^ 1, kt + 1);
      const int k0 = kt << 6;
      const ushort* Ksc = Ks[cur];
      const ushort* Vsc = Vs[cur];
#pragma unroll
      for (int kblk = 0; kblk < 2; ++kblk) {
        const int kbase = k0 + kblk * 32;
        if (kbase <= q0w + 31) {  // wave-uniform: skip fully-masked 32-blocks
          // ---- S^T[32k][32q] = K_blk · Q^T ----
          f32x16 st = {};
          __builtin_amdgcn_s_setprio(1);
#pragma unroll
          for (int dblk = 0; dblk < 4; ++dblk) {
            const int row = kblk * 32 + l31;
            bf16x8 ka = *(const bf16x8*)&Ksc[row * 64 + (((dblk * 2 + l5) ^ (row & 7)) * 8)];
            st = MFMA32(ka, qf[dblk], st);
          }
          __builtin_amdgcn_s_setprio(0);
          // ---- causal mask (diagonal blocks only); k = kbase+(r&3)+8*(r>>2)+4*l5 ----
          if (kbase + 31 > q0w) {
#pragma unroll
            for (int r = 0; r < 16; ++r) {
              const int kk = kbase + (r & 3) + 8 * (r >> 2) + 4 * l5;
              st[r] = (kk <= qlane) ? st[r] : -INFINITY;
            }
          }
          // ---- p = 2^s (max-free), lane-local row-sum ----
          float p[16];
#pragma unroll
          for (int r = 0; r < 16; ++r) {
            p[r] = __builtin_amdgcn_exp2f(st[r]);
            lsum += p[r];
          }
          // ---- pack P into PV A-fragments: cvt_pk + permlane32_swap ----
#pragma unroll
          for (int sbl = 0; sbl < 2; ++sbl) {
            uint32_t P0 = cvtpk(p[8 * sbl + 0], p[8 * sbl + 1]);
            uint32_t P1 = cvtpk(p[8 * sbl + 2], p[8 * sbl + 3]);
            uint32_t P2 = cvtpk(p[8 * sbl + 4], p[8 * sbl + 5]);
            uint32_t P3 = cvtpk(p[8 * sbl + 6], p[8 * sbl + 7]);
            plswap(P0, P2);  // P0={P0.lo,P2.lo}=word0, P2={P0.hi,P2.hi}=word2
            plswap(P1, P3);
            union { uint32_t u[4]; bf16x8 v; } pk;
            pk.u[0] = P0; pk.u[1] = P1; pk.u[2] = P2; pk.u[3] = P3;
            const int kchunk = kblk * 4 + sbl * 2 + l5;
            __builtin_amdgcn_s_setprio(1);
#pragma unroll
            for (int db2 = 0; db2 < 2; ++db2) {
              const int vrow = db2 * 32 + l31;
              bf16x8 vb = *(const bf16x8*)&Vsc[vrow * 64 + ((kchunk ^ (vrow & 7)) * 8)];
              if (db2 == 0) o0 = MFMA32(pk.v, vb, o0);
              else          o1 = MFMA32(pk.v, vb, o1);
            }
            __builtin_amdgcn_s_setprio(0);
          }
        }
      }
      __syncthreads();  // drains staging vmcnt; protects buffer reuse
    }

    // ---- epilogue: l redistribution + normalized store ----
    const float lfull = lsum + __shfl_xor(lsum, 32);
    if (lane < 32) l_lds[w][lane] = 1.f / lfull;
    // (wave-local LDS dependency; compiler inserts lgkmcnt wait)
#pragma unroll
    for (int r = 0; r < 16; ++r) {
      const int qoff = (r & 3) + 8 * (r >> 2) + 4 * l5;
      const float inv = l_lds[w][qoff];
      const int t = q0w + qoff;
      ushort* op = &O[(size_t)(bb * 2048 + t) * 1024 + h * 64 + l31];
      op[0] = f2b(o0[r] * inv);
      op[32] = f2b(o1[r] * inv);
    }
  }
#undef STAGE
}

extern "C" void kernel_launch(void* const* d_in, const int* in_sizes, int n_in,
                              void* d_out, int out_size, void* d_ws, size_t ws_size,
                              hipStream_t stream) {
  const float* x = (const float*)d_in[0];
  const float* w_qkv = (const float*)d_in[1];
  const float* b_qkv = (const float*)d_in[2];
  const float* w_proj = (const float*)d_in[3];
  const float* b_proj = (const float*)d_in[4];
  float* out = (float*)d_out;

  char* ws = (char*)d_ws;
  const size_t SZ_X = (size_t)8192 * 1024 * 2;
  const size_t SZ_WQ = (size_t)3072 * 1024 * 2;
  const size_t SZ_WP = (size_t)1024 * 1024 * 2;
  ushort* xb = (ushort*)(ws);                         // x bf16; later reused as attn-out
  ushort* wqb = (ushort*)(ws + SZ_X);
  ushort* wpb = (ushort*)(ws + SZ_X + SZ_WQ);
  ushort* q_ws = (ushort*)(ws + SZ_X + SZ_WQ + SZ_WP);
  ushort* k_ws = q_ws + (size_t)8192 * 1024;
  ushort* v_ws = k_ws + (size_t)8192 * 1024;          // V^T [bh][64][2048]

  cvt_f32_bf16<<<8388608 / 4 / 256, 256, 0, stream>>>(x, xb, 8388608 / 4);
  cvt_f32_bf16<<<3145728 / 4 / 256, 256, 0, stream>>>(w_qkv, wqb, 3145728 / 4);
  cvt_f32_bf16<<<1048576 / 4 / 256, 256, 0, stream>>>(w_proj, wpb, 1048576 / 4);

  // QKV: M=8192 N=3072 K=1024, scatter epilogue (Q pre-scaled, V transposed)
  gemm_bt<0><<<dim3(3072 / 128, 8192 / 128), 256, 0, stream>>>(
      xb, wqb, b_qkv, 8192, 3072, 1024, q_ws, k_ws, v_ws, nullptr);

  // attention: bh = blk&63 (XCD co-location), 8 strip-pairs per bh
  attn_v5<<<512, 256, 0, stream>>>(q_ws, k_ws, v_ws, xb);

  // proj: M=8192 N=1024 K=1024, fp32 + bias to d_out
  gemm_bt<1><<<dim3(1024 / 128, 8192 / 128), 256, 0, stream>>>(
      xb, wpb, b_proj, 8192, 1024, 1024, nullptr, nullptr, nullptr, out);
}

// Round 6
// 183.937 us; speedup vs baseline: 2.1867x; 1.0189x over previous
//
#include <hip/hip_runtime.h>
#include <hip/hip_bf16.h>
#include <cstdint>

typedef __attribute__((ext_vector_type(8))) short bf16x8;
typedef __attribute__((ext_vector_type(4))) float f32x4;
typedef __attribute__((ext_vector_type(16))) float f32x16;

#define MFMA16(a, b, c) __builtin_amdgcn_mfma_f32_16x16x32_bf16(a, b, c, 0, 0, 0)
#define MFMA32(a, b, c) __builtin_amdgcn_mfma_f32_32x32x16_bf16(a, b, c, 0, 0, 0)

typedef __attribute__((address_space(1))) uint32_t as1_u32;
typedef __attribute__((address_space(3))) uint32_t as3_u32;
static __device__ __forceinline__ void gload16(const void* g, void* l) {
  __builtin_amdgcn_global_load_lds((as1_u32*)g, (as3_u32*)l, 16, 0, 0);
}

static __device__ __forceinline__ ushort f2b(float f) {
  union { float f; uint32_t u; } v; v.f = f;
  uint32_t u = v.u;
  uint32_t r = (u + 0x7FFFu + ((u >> 16) & 1u)) >> 16;
  return (ushort)r;
}

// D.lo16 = bf16(a), D.hi16 = bf16(b)  (RNE)
static __device__ __forceinline__ uint32_t cvtpk(float a, float b) {
  uint32_t r;
  asm("v_cvt_pk_bf16_f32 %0, %1, %2" : "=v"(r) : "v"(a), "v"(b));
  return r;
}
// ISA: for i<32: tmp=a[i+32]; a[i+32]=b[i]; b[i]=tmp  ->  a'={a.lo,b.lo}, b'={a.hi,b.hi}
static __device__ __forceinline__ void plswap(uint32_t& a, uint32_t& b) {
  asm volatile("v_permlane32_swap_b32 %0, %1" : "+v"(a), "+v"(b));
}

// 0.125 (1/sqrt(64)) * log2(e): folded into Q so attn uses exp2 directly
#define QSCALE 0.1803368782f

// ---------- fp32 -> bf16 convert (n4 = n/4 float4 chunks) ----------
__global__ void cvt_f32_bf16(const float* __restrict__ in, ushort* __restrict__ out, int n4) {
  int i = blockIdx.x * blockDim.x + threadIdx.x;
  if (i >= n4) return;
  const float4 v = ((const float4*)in)[i];
  ushort4 o;
  o.x = f2b(v.x); o.y = f2b(v.y); o.z = f2b(v.z); o.w = f2b(v.w);
  ((ushort4*)out)[i] = o;
}

// ---------- GEMM v2: 128x128 tile, BK=32, 4-buffer counted-vmcnt pipeline ----------
// LDS tile layout: row-pairs packed into 128B physical rows with chunk-XOR swizzle:
//   elem(r, k) at  prow*64 + (((r&1)*4 + k/8) ^ (prow&7))*8 + k%8,  prow = r>>1
// -> fragment reads (16 consecutive rows, fixed k-chunk) are 2-way aliased = free.
// Staged via inverse-permuted GLOBAL source + linear LDS dest (both-sides rule).
// Pipeline: stage t+3 / compute t / vmcnt(8) (never 0 in steady state) / s_barrier.
// EPI=0: scatter q (pre-scaled), k -> [B*H][T][64]; v -> V^T [B*H][64][T]
// EPI=1: fp32 out [M][N]
template<int EPI>
__global__ __launch_bounds__(256) void gemm_bt(
    const ushort* __restrict__ A,    // [M][K] bf16
    const ushort* __restrict__ W,    // [N][K] bf16
    const float* __restrict__ bias,  // [N]
    int M, int N, int K,
    ushort* __restrict__ q_ws, ushort* __restrict__ k_ws, ushort* __restrict__ v_ws,
    float* __restrict__ out) {
  __shared__ ushort As[4][64 * 64];  // 4 buffers x 8KB (128 rows x 32 k, swizzled)
  __shared__ ushort Bs[4][64 * 64];
  const int tid = threadIdx.x;
  const int nbx = N >> 7;
  const int cpx = gridDim.x >> 3;   // bijective XCD chunking (gridDim.x % 8 == 0)
  const int wg = (blockIdx.x & 7) * cpx + (blockIdx.x >> 3);
  const int m0 = (wg / nbx) * 128, n0 = (wg % nbx) * 128;
  const int lane = tid & 63, w = tid >> 6;
  const int lr = lane & 15, lg = lane >> 4;
  const int wm = (w >> 1) * 64, wn = (w & 1) * 64;
  f32x4 acc[4][4] = {};

  const int nt = K >> 5;  // 32 k-tiles

#define GSTAGE(buf_, kt_)                                                   \
  do {                                                                      \
    const ushort* Asrc = A + (size_t)m0 * K + (kt_) * 32;                   \
    const ushort* Bsrc = W + (size_t)n0 * K + (kt_) * 32;                   \
    _Pragma("unroll") for (int i_ = 0; i_ < 2; ++i_) {                      \
      const int ch = i_ * 256 + tid;           /* 0..511 */                 \
      const int prow = ch >> 3, pchk = ch & 7;                              \
      const int lchk = pchk ^ (prow & 7);      /* inverse swizzle */        \
      const int r = prow * 2 + (lchk >> 2), kc = (lchk & 3) * 8;            \
      gload16(&Asrc[(size_t)r * K + kc], &As[buf_][ch * 8]);                \
      gload16(&Bsrc[(size_t)r * K + kc], &Bs[buf_][ch * 8]);                \
    }                                                                       \
  } while (0)

  // prologue: 3 tiles in flight; wait for tile 0 (12 loads out, drain to 8)
  GSTAGE(0, 0);
  GSTAGE(1, 1);
  GSTAGE(2, 2);
  asm volatile("s_waitcnt vmcnt(8)" ::: "memory");
  __builtin_amdgcn_s_barrier();
  asm volatile("" ::: "memory");

  for (int t = 0; t < nt; ++t) {
    if (t + 3 < nt) GSTAGE((t + 3) & 3, t + 3);
    const ushort* Asc = As[t & 3];
    const ushort* Bsc = Bs[t & 3];
    bf16x8 a[4], b[4];
#pragma unroll
    for (int mi = 0; mi < 4; ++mi) {
      const int r = wm + mi * 16 + lr;
      a[mi] = *(const bf16x8*)&Asc[(r >> 1) * 64 + (((((r & 1) << 2) | lg) ^ ((r >> 1) & 7)) * 8)];
    }
#pragma unroll
    for (int ni = 0; ni < 4; ++ni) {
      const int r = wn + ni * 16 + lr;
      b[ni] = *(const bf16x8*)&Bsc[(r >> 1) * 64 + (((((r & 1) << 2) | lg) ^ ((r >> 1) & 7)) * 8)];
    }
    __builtin_amdgcn_s_setprio(1);
#pragma unroll
    for (int mi = 0; mi < 4; ++mi)
#pragma unroll
      for (int ni = 0; ni < 4; ++ni)
        acc[mi][ni] = MFMA16(a[mi], b[ni], acc[mi][ni]);
    __builtin_amdgcn_s_setprio(0);
    // counted waits: t+1's loads done; t+2/t+3 stay in flight (never vmcnt(0) mid-loop)
    if (t + 3 < nt)
      asm volatile("s_waitcnt vmcnt(8)" ::: "memory");
    else if (t + 2 < nt)
      asm volatile("s_waitcnt vmcnt(4)" ::: "memory");
    else if (t + 1 < nt)
      asm volatile("s_waitcnt vmcnt(0)" ::: "memory");
    __builtin_amdgcn_s_barrier();
    asm volatile("" ::: "memory");
  }
#undef GSTAGE

#pragma unroll
  for (int mi = 0; mi < 4; ++mi) {
#pragma unroll
    for (int ni = 0; ni < 4; ++ni) {
      const int rowb = m0 + wm + mi * 16 + lg * 4;  // C/D: row=(lane>>4)*4+reg, col=lane&15
      const int col = n0 + wn + ni * 16 + lr;
      float v[4];
#pragma unroll
      for (int i = 0; i < 4; ++i) v[i] = acc[mi][ni][i] + bias[col];
      if (EPI == 0) {
        const int sel = col >> 10;        // uniform per block
        const int rem = col & 1023;
        const int h = rem >> 6, d = rem & 63;
        const int bb = rowb >> 11, t0 = rowb & 2047;
        if (sel == 2) {
          ushort4 st;
          st.x = f2b(v[0]); st.y = f2b(v[1]); st.z = f2b(v[2]); st.w = f2b(v[3]);
          *(ushort4*)&v_ws[((size_t)(bb * 16 + h) * 64 + d) * 2048 + t0] = st;
        } else if (sel == 0) {
#pragma unroll
          for (int i = 0; i < 4; ++i)
            q_ws[((size_t)(bb * 16 + h) * 2048 + t0 + i) * 64 + d] = f2b(v[i] * QSCALE);
        } else {
#pragma unroll
          for (int i = 0; i < 4; ++i)
            k_ws[((size_t)(bb * 16 + h) * 2048 + t0 + i) * 64 + d] = f2b(v[i]);
        }
      } else {
#pragma unroll
        for (int i = 0; i < 4; ++i)
          out[(size_t)(rowb + i) * N + col] = v[i];
      }
    }
  }
}

// ---------- causal flash attention v5: swapped QK^T, in-register softmax ----------
// block = 4 waves x 32 q rows = 128 q (one strip); two strips (15-pr, pr) per block.
// K/V LDS-staged (XOR-swizzled, double-buffered). bh = blk&63 -> same-bh on same XCD.
__global__ __launch_bounds__(256) void attn_v5(
    const ushort* __restrict__ Q, const ushort* __restrict__ K,
    const ushort* __restrict__ VT, ushort* __restrict__ O /* [B][T][C] bf16 */) {
  const int blk = blockIdx.x;
  const int bh = blk & 63;   // mod-8-equal ids land on one XCD: K/V L2-resident
  const int pr = blk >> 6;   // 0..7
  const int tid = threadIdx.x;
  const int w = tid >> 6, lane = tid & 63;
  const int l31 = lane & 31, l5 = lane >> 5;
  const int bb = bh >> 4, h = bh & 15;
  const size_t base = (size_t)bh * 2048 * 64;
  const ushort* Qb = Q + base;
  const ushort* Kb = K + base;
  const ushort* VTb = VT + base;  // [64][2048]

  __shared__ ushort Ks[2][64 * 64];  // [k-row][d], chunk-swizzled
  __shared__ ushort Vs[2][64 * 64];  // [d-row][k], chunk-swizzled
  __shared__ float l_lds[4][32];

#define STAGE(buf, kt_)                                              \
  do {                                                               \
    const ushort* Kt = Kb + (size_t)(kt_) * 64 * 64;                 \
    const ushort* Vt = VTb + (kt_) * 64;                             \
    _Pragma("unroll") for (int i_ = 0; i_ < 2; ++i_) {               \
      const int ch = i_ * 256 + tid;                                 \
      const int r = ch >> 3;                                         \
      const int csw = ((ch & 7) ^ (r & 7)) * 8;                      \
      gload16(&Kt[(size_t)r * 64 + csw], &Ks[buf][ch * 8]);          \
      gload16(&Vt[(size_t)r * 2048 + csw], &Vs[buf][ch * 8]);        \
    }                                                                \
  } while (0)

#pragma unroll 1
  for (int ph = 0; ph < 2; ++ph) {
    const int s = ph ? pr : 15 - pr;  // strip pairing: 34 tiles/block total
    const int q0w = s * 128 + w * 32;
    const int nt = 2 * s + 2;
    const int qlane = q0w + l31;  // this lane's q-column in S^T

    // Q as B-fragments: lane holds Q[qlane][dblk*16 + l5*8 + j]
    bf16x8 qf[4];
#pragma unroll
    for (int dblk = 0; dblk < 4; ++dblk)
      qf[dblk] = *(const bf16x8*)&Qb[(size_t)qlane * 64 + dblk * 16 + l5 * 8];

    f32x16 o0 = {}, o1 = {};
    float lsum = 0.f;

    STAGE(0, 0);
    __syncthreads();

    for (int kt = 0; kt < nt; ++kt) {
      const int cur = kt & 1;
      if (kt + 1 < nt) STAGE(cur ^ 1, kt + 1);
      const int k0 = kt << 6;
      const ushort* Ksc = Ks[cur];
      const ushort* Vsc = Vs[cur];
#pragma unroll
      for (int kblk = 0; kblk < 2; ++kblk) {
        const int kbase = k0 + kblk * 32;
        if (kbase <= q0w + 31) {  // wave-uniform: skip fully-masked 32-blocks
          // ---- S^T[32k][32q] = K_blk · Q^T ----
          f32x16 st = {};
          __builtin_amdgcn_s_setprio(1);
#pragma unroll
          for (int dblk = 0; dblk < 4; ++dblk) {
            const int row = kblk * 32 + l31;
            bf16x8 ka = *(const bf16x8*)&Ksc[row * 64 + (((dblk * 2 + l5) ^ (row & 7)) * 8)];
            st = MFMA32(ka, qf[dblk], st);
          }
          __builtin_amdgcn_s_setprio(0);
          // ---- causal mask (diagonal blocks only); k = kbase+(r&3)+8*(r>>2)+4*l5 ----
          if (kbase + 31 > q0w) {
#pragma unroll
            for (int r = 0; r < 16; ++r) {
              const int kk = kbase + (r & 3) + 8 * (r >> 2) + 4 * l5;
              st[r] = (kk <= qlane) ? st[r] : -INFINITY;
            }
          }
          // ---- p = 2^s (max-free), lane-local row-sum ----
          float p[16];
#pragma unroll
          for (int r = 0; r < 16; ++r) {
            p[r] = __builtin_amdgcn_exp2f(st[r]);
            lsum += p[r];
          }
          // ---- pack P into PV A-fragments: cvt_pk + permlane32_swap ----
#pragma unroll
          for (int sbl = 0; sbl < 2; ++sbl) {
            uint32_t P0 = cvtpk(p[8 * sbl + 0], p[8 * sbl + 1]);
            uint32_t P1 = cvtpk(p[8 * sbl + 2], p[8 * sbl + 3]);
            uint32_t P2 = cvtpk(p[8 * sbl + 4], p[8 * sbl + 5]);
            uint32_t P3 = cvtpk(p[8 * sbl + 6], p[8 * sbl + 7]);
            plswap(P0, P2);  // P0={P0.lo,P2.lo}=word0, P2={P0.hi,P2.hi}=word2
            plswap(P1, P3);
            union { uint32_t u[4]; bf16x8 v; } pk;
            pk.u[0] = P0; pk.u[1] = P1; pk.u[2] = P2; pk.u[3] = P3;
            const int kchunk = kblk * 4 + sbl * 2 + l5;
            __builtin_amdgcn_s_setprio(1);
#pragma unroll
            for (int db2 = 0; db2 < 2; ++db2) {
              const int vrow = db2 * 32 + l31;
              bf16x8 vb = *(const bf16x8*)&Vsc[vrow * 64 + ((kchunk ^ (vrow & 7)) * 8)];
              if (db2 == 0) o0 = MFMA32(pk.v, vb, o0);
              else          o1 = MFMA32(pk.v, vb, o1);
            }
            __builtin_amdgcn_s_setprio(0);
          }
        }
      }
      __syncthreads();  // drains staging vmcnt; protects buffer reuse
    }

    // ---- epilogue: l redistribution + normalized store ----
    const float lfull = lsum + __shfl_xor(lsum, 32);
    if (lane < 32) l_lds[w][lane] = 1.f / lfull;
    // (wave-local LDS dependency; compiler inserts lgkmcnt wait)
#pragma unroll
    for (int r = 0; r < 16; ++r) {
      const int qoff = (r & 3) + 8 * (r >> 2) + 4 * l5;
      const float inv = l_lds[w][qoff];
      const int t = q0w + qoff;
      ushort* op = &O[(size_t)(bb * 2048 + t) * 1024 + h * 64 + l31];
      op[0] = f2b(o0[r] * inv);
      op[32] = f2b(o1[r] * inv);
    }
  }
#undef STAGE
}

extern "C" void kernel_launch(void* const* d_in, const int* in_sizes, int n_in,
                              void* d_out, int out_size, void* d_ws, size_t ws_size,
                              hipStream_t stream) {
  const float* x = (const float*)d_in[0];
  const float* w_qkv = (const float*)d_in[1];
  const float* b_qkv = (const float*)d_in[2];
  const float* w_proj = (const float*)d_in[3];
  const float* b_proj = (const float*)d_in[4];
  float* out = (float*)d_out;

  char* ws = (char*)d_ws;
  const size_t SZ_X = (size_t)8192 * 1024 * 2;
  const size_t SZ_WQ = (size_t)3072 * 1024 * 2;
  const size_t SZ_WP = (size_t)1024 * 1024 * 2;
  ushort* xb = (ushort*)(ws);                         // x bf16; later reused as attn-out
  ushort* wqb = (ushort*)(ws + SZ_X);
  ushort* wpb = (ushort*)(ws + SZ_X + SZ_WQ);
  ushort* q_ws = (ushort*)(ws + SZ_X + SZ_WQ + SZ_WP);
  ushort* k_ws = q_ws + (size_t)8192 * 1024;
  ushort* v_ws = k_ws + (size_t)8192 * 1024;          // V^T [bh][64][2048]

  cvt_f32_bf16<<<8388608 / 4 / 256, 256, 0, stream>>>(x, xb, 8388608 / 4);
  cvt_f32_bf16<<<3145728 / 4 / 256, 256, 0, stream>>>(w_qkv, wqb, 3145728 / 4);
  cvt_f32_bf16<<<1048576 / 4 / 256, 256, 0, stream>>>(w_proj, wpb, 1048576 / 4);

  // QKV: M=8192 N=3072 K=1024 (1536 blocks, %8==0 -> bijective XCD chunking)
  gemm_bt<0><<<1536, 256, 0, stream>>>(
      xb, wqb, b_qkv, 8192, 3072, 1024, q_ws, k_ws, v_ws, nullptr);

  // attention: bh = blk&63 (XCD co-location), 8 strip-pairs per bh
  attn_v5<<<512, 256, 0, stream>>>(q_ws, k_ws, v_ws, xb);

  // proj: M=8192 N=1024 K=1024 (512 blocks)
  gemm_bt<1><<<512, 256, 0, stream>>>(
      xb, wpb, b_proj, 8192, 1024, 1024, nullptr, nullptr, nullptr, out);
}

// Round 7
// 169.774 us; speedup vs baseline: 2.3692x; 1.0834x over previous
//
#include <hip/hip_runtime.h>
#include <hip/hip_bf16.h>
#include <cstdint>

typedef __attribute__((ext_vector_type(8))) short bf16x8;
typedef __attribute__((ext_vector_type(4))) float f32x4;
typedef __attribute__((ext_vector_type(16))) float f32x16;

#define MFMA16(a, b, c) __builtin_amdgcn_mfma_f32_16x16x32_bf16(a, b, c, 0, 0, 0)
#define MFMA32(a, b, c) __builtin_amdgcn_mfma_f32_32x32x16_bf16(a, b, c, 0, 0, 0)

typedef __attribute__((address_space(1))) uint32_t as1_u32;
typedef __attribute__((address_space(3))) uint32_t as3_u32;
static __device__ __forceinline__ void gload16(const void* g, void* l) {
  __builtin_amdgcn_global_load_lds((as1_u32*)g, (as3_u32*)l, 16, 0, 0);
}

static __device__ __forceinline__ ushort f2b(float f) {
  union { float f; uint32_t u; } v; v.f = f;
  uint32_t u = v.u;
  uint32_t r = (u + 0x7FFFu + ((u >> 16) & 1u)) >> 16;
  return (ushort)r;
}

// D.lo16 = bf16(a), D.hi16 = bf16(b)  (RNE)
static __device__ __forceinline__ uint32_t cvtpk(float a, float b) {
  uint32_t r;
  asm("v_cvt_pk_bf16_f32 %0, %1, %2" : "=v"(r) : "v"(a), "v"(b));
  return r;
}
// ISA: for i<32: tmp=a[i+32]; a[i+32]=b[i]; b[i]=tmp  ->  a'={a.lo,b.lo}, b'={a.hi,b.hi}
static __device__ __forceinline__ void plswap(uint32_t& a, uint32_t& b) {
  asm volatile("v_permlane32_swap_b32 %0, %1" : "+v"(a), "+v"(b));
}

// 0.125 (1/sqrt(64)) * log2(e): folded into Q so attn uses exp2 directly
#define QSCALE 0.1803368782f

// ---------- fp32 -> bf16 convert (n4 = n/4 float4 chunks) ----------
__global__ void cvt_f32_bf16(const float* __restrict__ in, ushort* __restrict__ out, int n4) {
  int i = blockIdx.x * blockDim.x + threadIdx.x;
  if (i >= n4) return;
  const float4 v = ((const float4*)in)[i];
  ushort4 o;
  o.x = f2b(v.x); o.y = f2b(v.y); o.z = f2b(v.z); o.w = f2b(v.w);
  ((ushort4*)out)[i] = o;
}

// ---------- GEMM v3: 128x128 tile, BK=32, 3-buffer counted-vmcnt pipeline ----------
// 48KB LDS -> 3 blocks/CU (inter-block overlap, m97/m114 mechanism) + swizzle (0
// conflicts, verified R6) + counted vmcnt (never 0 mid-loop).
// LDS layout: row-pairs packed into 128B physical rows, chunk-XOR swizzled:
//   elem(r, k) at  prow*64 + (((r&1)*4 + k/8) ^ (prow&7))*8 + k%8,  prow = r>>1
// Staged via inverse-permuted GLOBAL source + linear LDS dest (both-sides rule).
// EPI=0: scatter q (pre-scaled), k -> [B*H][T][64]; v -> V^T [B*H][64][T]
// EPI=1: fp32 out [M][N]
template<int EPI>
__global__ __launch_bounds__(256) void gemm_bt(
    const ushort* __restrict__ A,    // [M][K] bf16
    const ushort* __restrict__ W,    // [N][K] bf16
    const float* __restrict__ bias,  // [N]
    int M, int N, int K,
    ushort* __restrict__ q_ws, ushort* __restrict__ k_ws, ushort* __restrict__ v_ws,
    float* __restrict__ out) {
  __shared__ ushort As[3][64 * 64];  // 3 buffers x 8KB each matrix (48KB total)
  __shared__ ushort Bs[3][64 * 64];
  const int tid = threadIdx.x;
  const int nbx = N >> 7;
  const int cpx = gridDim.x >> 3;   // bijective XCD chunking (gridDim.x % 8 == 0)
  const int wg = (blockIdx.x & 7) * cpx + (blockIdx.x >> 3);
  const int m0 = (wg / nbx) * 128, n0 = (wg % nbx) * 128;
  const int lane = tid & 63, w = tid >> 6;
  const int lr = lane & 15, lg = lane >> 4;
  const int wm = (w >> 1) * 64, wn = (w & 1) * 64;
  f32x4 acc[4][4] = {};

  const int nt = K >> 5;  // k-tiles of 32

#define GSTAGE(buf_, kt_)                                                   \
  do {                                                                      \
    const ushort* Asrc = A + (size_t)m0 * K + (kt_) * 32;                   \
    const ushort* Bsrc = W + (size_t)n0 * K + (kt_) * 32;                   \
    _Pragma("unroll") for (int i_ = 0; i_ < 2; ++i_) {                      \
      const int ch = i_ * 256 + tid;           /* 0..511 */                 \
      const int prow = ch >> 3, pchk = ch & 7;                              \
      const int lchk = pchk ^ (prow & 7);      /* inverse swizzle */        \
      const int r = prow * 2 + (lchk >> 2), kc = (lchk & 3) * 8;            \
      gload16(&Asrc[(size_t)r * K + kc], &As[buf_][ch * 8]);                \
      gload16(&Bsrc[(size_t)r * K + kc], &Bs[buf_][ch * 8]);                \
    }                                                                       \
  } while (0)

  // prologue: 2 tiles in flight; drain to tile 0 done (8 loads out -> 4)
  GSTAGE(0, 0);
  GSTAGE(1, 1);
  asm volatile("s_waitcnt vmcnt(4)" ::: "memory");
  __builtin_amdgcn_s_barrier();
  asm volatile("" ::: "memory");

  int bcur = 0, bnxt = 2;  // t%3 and (t+2)%3, maintained incrementally
  for (int t = 0; t < nt; ++t) {
    if (t + 2 < nt) GSTAGE(bnxt, t + 2);
    const ushort* Asc = As[bcur];
    const ushort* Bsc = Bs[bcur];
    bf16x8 a[4], b[4];
#pragma unroll
    for (int mi = 0; mi < 4; ++mi) {
      const int r = wm + mi * 16 + lr;
      a[mi] = *(const bf16x8*)&Asc[(r >> 1) * 64 + (((((r & 1) << 2) | lg) ^ ((r >> 1) & 7)) * 8)];
    }
#pragma unroll
    for (int ni = 0; ni < 4; ++ni) {
      const int r = wn + ni * 16 + lr;
      b[ni] = *(const bf16x8*)&Bsc[(r >> 1) * 64 + (((((r & 1) << 2) | lg) ^ ((r >> 1) & 7)) * 8)];
    }
    __builtin_amdgcn_s_setprio(1);
#pragma unroll
    for (int mi = 0; mi < 4; ++mi)
#pragma unroll
      for (int ni = 0; ni < 4; ++ni)
        acc[mi][ni] = MFMA16(a[mi], b[ni], acc[mi][ni]);
    __builtin_amdgcn_s_setprio(0);
    // counted waits: t+1's 4 loads done; t+2's stay in flight (never 0 mid-loop)
    if (t + 2 < nt)
      asm volatile("s_waitcnt vmcnt(4)" ::: "memory");
    else if (t + 1 < nt)
      asm volatile("s_waitcnt vmcnt(0)" ::: "memory");
    if (t + 1 < nt) {
      __builtin_amdgcn_s_barrier();
      asm volatile("" ::: "memory");
    }
    bcur = (bcur == 2) ? 0 : bcur + 1;
    bnxt = (bnxt == 2) ? 0 : bnxt + 1;
  }
#undef GSTAGE

#pragma unroll
  for (int mi = 0; mi < 4; ++mi) {
#pragma unroll
    for (int ni = 0; ni < 4; ++ni) {
      const int rowb = m0 + wm + mi * 16 + lg * 4;  // C/D: row=(lane>>4)*4+reg, col=lane&15
      const int col = n0 + wn + ni * 16 + lr;
      float v[4];
#pragma unroll
      for (int i = 0; i < 4; ++i) v[i] = acc[mi][ni][i] + bias[col];
      if (EPI == 0) {
        const int sel = col >> 10;        // uniform per block
        const int rem = col & 1023;
        const int h = rem >> 6, d = rem & 63;
        const int bb = rowb >> 11, t0 = rowb & 2047;
        if (sel == 2) {
          ushort4 st;
          st.x = f2b(v[0]); st.y = f2b(v[1]); st.z = f2b(v[2]); st.w = f2b(v[3]);
          *(ushort4*)&v_ws[((size_t)(bb * 16 + h) * 64 + d) * 2048 + t0] = st;
        } else if (sel == 0) {
#pragma unroll
          for (int i = 0; i < 4; ++i)
            q_ws[((size_t)(bb * 16 + h) * 2048 + t0 + i) * 64 + d] = f2b(v[i] * QSCALE);
        } else {
#pragma unroll
          for (int i = 0; i < 4; ++i)
            k_ws[((size_t)(bb * 16 + h) * 2048 + t0 + i) * 64 + d] = f2b(v[i]);
        }
      } else {
#pragma unroll
        for (int i = 0; i < 4; ++i)
          out[(size_t)(rowb + i) * N + col] = v[i];
      }
    }
  }
}

// ---------- causal flash attention v5: swapped QK^T, in-register softmax ----------
// block = 4 waves x 32 q rows = 128 q (one strip); two strips (15-pr, pr) per block.
// K/V LDS-staged (XOR-swizzled, double-buffered). bh = blk&63 -> same-bh on same XCD.
__global__ __launch_bounds__(256) void attn_v5(
    const ushort* __restrict__ Q, const ushort* __restrict__ K,
    const ushort* __restrict__ VT, ushort* __restrict__ O /* [B][T][C] bf16 */) {
  const int blk = blockIdx.x;
  const int bh = blk & 63;   // mod-8-equal ids land on one XCD: K/V L2-resident
  const int pr = blk >> 6;   // 0..7
  const int tid = threadIdx.x;
  const int w = tid >> 6, lane = tid & 63;
  const int l31 = lane & 31, l5 = lane >> 5;
  const int bb = bh >> 4, h = bh & 15;
  const size_t base = (size_t)bh * 2048 * 64;
  const ushort* Qb = Q + base;
  const ushort* Kb = K + base;
  const ushort* VTb = VT + base;  // [64][2048]

  __shared__ ushort Ks[2][64 * 64];  // [k-row][d], chunk-swizzled
  __shared__ ushort Vs[2][64 * 64];  // [d-row][k], chunk-swizzled
  __shared__ float l_lds[4][32];

#define STAGE(buf, kt_)                                              \
  do {                                                               \
    const ushort* Kt = Kb + (size_t)(kt_) * 64 * 64;                 \
    const ushort* Vt = VTb + (kt_) * 64;                             \
    _Pragma("unroll") for (int i_ = 0; i_ < 2; ++i_) {               \
      const int ch = i_ * 256 + tid;                                 \
      const int r = ch >> 3;                                         \
      const int csw = ((ch & 7) ^ (r & 7)) * 8;                      \
      gload16(&Kt[(size_t)r * 64 + csw], &Ks[buf][ch * 8]);          \
      gload16(&Vt[(size_t)r * 2048 + csw], &Vs[buf][ch * 8]);        \
    }                                                                \
  } while (0)

#pragma unroll 1
  for (int ph = 0; ph < 2; ++ph) {
    const int s = ph ? pr : 15 - pr;  // strip pairing: 34 tiles/block total
    const int q0w = s * 128 + w * 32;
    const int nt = 2 * s + 2;
    const int qlane = q0w + l31;  // this lane's q-column in S^T

    // Q as B-fragments: lane holds Q[qlane][dblk*16 + l5*8 + j]
    bf16x8 qf[4];
#pragma unroll
    for (int dblk = 0; dblk < 4; ++dblk)
      qf[dblk] = *(const bf16x8*)&Qb[(size_t)qlane * 64 + dblk * 16 + l5 * 8];

    f32x16 o0 = {}, o1 = {};
    float lsum = 0.f;

    STAGE(0, 0);
    __syncthreads();

    for (int kt = 0; kt < nt; ++kt) {
      const int cur = kt & 1;
      if (kt + 1 < nt) STAGE(cur ^ 1, kt + 1);
      const int k0 = kt << 6;
      const ushort* Ksc = Ks[cur];
      const ushort* Vsc = Vs[cur];
#pragma unroll
      for (int kblk = 0; kblk < 2; ++kblk) {
        const int kbase = k0 + kblk * 32;
        if (kbase <= q0w + 31) {  // wave-uniform: skip fully-masked 32-blocks
          // ---- S^T[32k][32q] = K_blk · Q^T ----
          f32x16 st = {};
          __builtin_amdgcn_s_setprio(1);
#pragma unroll
          for (int dblk = 0; dblk < 4; ++dblk) {
            const int row = kblk * 32 + l31;
            bf16x8 ka = *(const bf16x8*)&Ksc[row * 64 + (((dblk * 2 + l5) ^ (row & 7)) * 8)];
            st = MFMA32(ka, qf[dblk], st);
          }
          __builtin_amdgcn_s_setprio(0);
          // ---- causal mask (diagonal blocks only); k = kbase+(r&3)+8*(r>>2)+4*l5 ----
          if (kbase + 31 > q0w) {
#pragma unroll
            for (int r = 0; r < 16; ++r) {
              const int kk = kbase + (r & 3) + 8 * (r >> 2) + 4 * l5;
              st[r] = (kk <= qlane) ? st[r] : -INFINITY;
            }
          }
          // ---- p = 2^s (max-free), lane-local row-sum ----
          float p[16];
#pragma unroll
          for (int r = 0; r < 16; ++r) {
            p[r] = __builtin_amdgcn_exp2f(st[r]);
            lsum += p[r];
          }
          // ---- pack P into PV A-fragments: cvt_pk + permlane32_swap ----
#pragma unroll
          for (int sbl = 0; sbl < 2; ++sbl) {
            uint32_t P0 = cvtpk(p[8 * sbl + 0], p[8 * sbl + 1]);
            uint32_t P1 = cvtpk(p[8 * sbl + 2], p[8 * sbl + 3]);
            uint32_t P2 = cvtpk(p[8 * sbl + 4], p[8 * sbl + 5]);
            uint32_t P3 = cvtpk(p[8 * sbl + 6], p[8 * sbl + 7]);
            plswap(P0, P2);  // P0={P0.lo,P2.lo}=word0, P2={P0.hi,P2.hi}=word2
            plswap(P1, P3);
            union { uint32_t u[4]; bf16x8 v; } pk;
            pk.u[0] = P0; pk.u[1] = P1; pk.u[2] = P2; pk.u[3] = P3;
            const int kchunk = kblk * 4 + sbl * 2 + l5;
            __builtin_amdgcn_s_setprio(1);
#pragma unroll
            for (int db2 = 0; db2 < 2; ++db2) {
              const int vrow = db2 * 32 + l31;
              bf16x8 vb = *(const bf16x8*)&Vsc[vrow * 64 + ((kchunk ^ (vrow & 7)) * 8)];
              if (db2 == 0) o0 = MFMA32(pk.v, vb, o0);
              else          o1 = MFMA32(pk.v, vb, o1);
            }
            __builtin_amdgcn_s_setprio(0);
          }
        }
      }
      __syncthreads();  // drains staging vmcnt; protects buffer reuse
    }

    // ---- epilogue: l redistribution + normalized store ----
    const float lfull = lsum + __shfl_xor(lsum, 32);
    if (lane < 32) l_lds[w][lane] = 1.f / lfull;
    // (wave-local LDS dependency; compiler inserts lgkmcnt wait)
#pragma unroll
    for (int r = 0; r < 16; ++r) {
      const int qoff = (r & 3) + 8 * (r >> 2) + 4 * l5;
      const float inv = l_lds[w][qoff];
      const int t = q0w + qoff;
      ushort* op = &O[(size_t)(bb * 2048 + t) * 1024 + h * 64 + l31];
      op[0] = f2b(o0[r] * inv);
      op[32] = f2b(o1[r] * inv);
    }
  }
#undef STAGE
}

extern "C" void kernel_launch(void* const* d_in, const int* in_sizes, int n_in,
                              void* d_out, int out_size, void* d_ws, size_t ws_size,
                              hipStream_t stream) {
  const float* x = (const float*)d_in[0];
  const float* w_qkv = (const float*)d_in[1];
  const float* b_qkv = (const float*)d_in[2];
  const float* w_proj = (const float*)d_in[3];
  const float* b_proj = (const float*)d_in[4];
  float* out = (float*)d_out;

  char* ws = (char*)d_ws;
  const size_t SZ_X = (size_t)8192 * 1024 * 2;
  const size_t SZ_WQ = (size_t)3072 * 1024 * 2;
  const size_t SZ_WP = (size_t)1024 * 1024 * 2;
  ushort* xb = (ushort*)(ws);                         // x bf16; later reused as attn-out
  ushort* wqb = (ushort*)(ws + SZ_X);
  ushort* wpb = (ushort*)(ws + SZ_X + SZ_WQ);
  ushort* q_ws = (ushort*)(ws + SZ_X + SZ_WQ + SZ_WP);
  ushort* k_ws = q_ws + (size_t)8192 * 1024;
  ushort* v_ws = k_ws + (size_t)8192 * 1024;          // V^T [bh][64][2048]

  cvt_f32_bf16<<<8388608 / 4 / 256, 256, 0, stream>>>(x, xb, 8388608 / 4);
  cvt_f32_bf16<<<3145728 / 4 / 256, 256, 0, stream>>>(w_qkv, wqb, 3145728 / 4);
  cvt_f32_bf16<<<1048576 / 4 / 256, 256, 0, stream>>>(w_proj, wpb, 1048576 / 4);

  // QKV: M=8192 N=3072 K=1024 (1536 blocks, %8==0 -> bijective XCD chunking)
  gemm_bt<0><<<1536, 256, 0, stream>>>(
      xb, wqb, b_qkv, 8192, 3072, 1024, q_ws, k_ws, v_ws, nullptr);

  // attention: bh = blk&63 (XCD co-location), 8 strip-pairs per bh
  attn_v5<<<512, 256, 0, stream>>>(q_ws, k_ws, v_ws, xb);

  // proj: M=8192 N=1024 K=1024 (512 blocks)
  gemm_bt<1><<<512, 256, 0, stream>>>(
      xb, wpb, b_proj, 8192, 1024, 1024, nullptr, nullptr, nullptr, out);
}